// Round 1
// baseline (105.752 us; speedup 1.0000x reference)
//
#include <hip/hip_runtime.h>

// KVCache scatter: B=8, L=4096, H=16, D=64, Q=1024 (fp32)
// out = [k_out (B,L,H,D) | v_out (B,L,H,D)] flat fp32
//
// Strategy: inverse-map fused write.
//   inv[b*L + l] = q if k_val[b,q] scatters to slot l, else -1.
//   One streaming kernel writes every output float4 exactly once,
//   choosing source = val row (if scattered) else cache row.
// Traffic: 268 MB write + ~268 MB read = 536 MB  (vs 670 MB two-pass).

#define KB 8
#define KL 4096
#define KH 16
#define KD 64
#define KQ 1024

static constexpr long long TOT = (long long)KB * KL * KH * KD;   // 33,554,432 floats per tensor
static constexpr int ROW4 = (KH * KD) / 4;                        // 256 float4 per (b,l) row

__global__ void build_inv_kernel(const int* __restrict__ pos, int* __restrict__ inv) {
    int i = blockIdx.x * blockDim.x + threadIdx.x;   // over B*Q
    if (i < KB * KQ) {
        int b = i / KQ;
        int q = i - b * KQ;
        int p = pos[i] - 1;                           // 1-indexed -> 0-indexed slot
        inv[b * KL + p] = q;
    }
}

__global__ void fused_write_kernel(const float4* __restrict__ kc, const float4* __restrict__ vc,
                                   const float4* __restrict__ kv, const float4* __restrict__ vv,
                                   const int* __restrict__ inv,
                                   float4* __restrict__ ko, float4* __restrict__ vo) {
    const long long n = TOT / 4;                      // 8,388,608 float4 per tensor
    const long long stride = (long long)gridDim.x * blockDim.x;
    for (long long i = (long long)blockIdx.x * blockDim.x + threadIdx.x; i < n; i += stride) {
        int bl     = (int)(i >> 8);                   // / ROW4 (=256)
        int within = (int)(i & (ROW4 - 1));
        int q = inv[bl];
        if (q >= 0) {
            int b = bl >> 12;                         // / KL (=4096)
            long long s = ((long long)(b * KQ + q) << 8) + within;
            ko[i] = kv[s];
            vo[i] = vv[s];
        } else {
            ko[i] = kc[i];
            vo[i] = vc[i];
        }
    }
}

// Fallback two-pass (only if ws too small for the 128 KB inverse map).
__global__ void copy_kernel(const float4* __restrict__ src, float4* __restrict__ dst, long long n) {
    const long long stride = (long long)gridDim.x * blockDim.x;
    for (long long i = (long long)blockIdx.x * blockDim.x + threadIdx.x; i < n; i += stride)
        dst[i] = src[i];
}

__global__ void scatter_kernel(const float4* __restrict__ kv, const float4* __restrict__ vv,
                               const int* __restrict__ pos,
                               float4* __restrict__ ko, float4* __restrict__ vo) {
    // one thread per float4 of k_val/v_val: B*Q*H*D/4 = 2,097,152
    long long i = (long long)blockIdx.x * blockDim.x + threadIdx.x;
    const long long n = (long long)KB * KQ * ROW4;
    if (i >= n) return;
    int bq     = (int)(i >> 8);
    int within = (int)(i & (ROW4 - 1));
    int b = bq >> 10;                                 // / KQ (=1024)
    int p = pos[bq] - 1;
    long long d = ((long long)(b * KL + p) << 8) + within;
    ko[d] = kv[i];
    vo[d] = vv[i];
}

extern "C" void kernel_launch(void* const* d_in, const int* in_sizes, int n_in,
                              void* d_out, int out_size, void* d_ws, size_t ws_size,
                              hipStream_t stream) {
    const float* kc  = (const float*)d_in[0];
    const float* vc  = (const float*)d_in[1];
    const float* kv  = (const float*)d_in[2];
    const float* vv  = (const float*)d_in[3];
    const int*   pos = (const int*)d_in[4];

    float* ko = (float*)d_out;
    float* vo = ko + TOT;

    const size_t inv_bytes = (size_t)KB * KL * sizeof(int);   // 128 KB

    if (ws_size >= inv_bytes) {
        int* inv = (int*)d_ws;
        hipMemsetAsync(inv, 0xFF, inv_bytes, stream);         // all -1
        build_inv_kernel<<<(KB * KQ + 255) / 256, 256, 0, stream>>>(pos, inv);
        fused_write_kernel<<<4096, 256, 0, stream>>>(
            (const float4*)kc, (const float4*)vc,
            (const float4*)kv, (const float4*)vv,
            inv, (float4*)ko, (float4*)vo);
    } else {
        const long long n4 = TOT / 4;
        copy_kernel<<<2048, 256, 0, stream>>>((const float4*)kc, (float4*)ko, n4);
        copy_kernel<<<2048, 256, 0, stream>>>((const float4*)vc, (float4*)vo, n4);
        const long long s4 = (long long)KB * KQ * ROW4;
        scatter_kernel<<<(int)((s4 + 255) / 256), 256, 0, stream>>>(
            (const float4*)kv, (const float4*)vv, pos, (float4*)ko, (float4*)vo);
    }
}

// Round 3
// 102.251 us; speedup vs baseline: 1.0342x; 1.0342x over previous
//
#include <hip/hip_runtime.h>

// KVCache scatter: B=8, L=4096, H=16, D=64, Q=1024 (fp32)
// out = [k_out (B,L,H,D) | v_out (B,L,H,D)] flat fp32
//
// Strategy: inverse-map fused write (2 launches total).
//   Kernel 1 (8 blocks, one per batch): init inv slice to -1, sync, scatter
//     batch-local positions. No cross-block race since scatter is batch-local.
//   Kernel 2: one streaming pass writes every output float4 exactly once,
//     sourcing from val row (if scattered) else cache row. Non-temporal
//     hints on all big streams (no reuse; avoid L3 thrash).
// Traffic floor: 268 MB write + 268 MB read = 536 MB -> 85 us @ 6.29 TB/s.
//
// NOTE: __builtin_nontemporal_* requires a clang vector type, not HIP's
// float4 class -> use ext_vector_type(4).

#define KB 8
#define KL 4096
#define KH 16
#define KD 64
#define KQ 1024

typedef float f32x4 __attribute__((ext_vector_type(4)));

static constexpr long long TOT = (long long)KB * KL * KH * KD;   // 33,554,432 floats per tensor
static constexpr int ROW4 = (KH * KD) / 4;                        // 256 f32x4 per (b,l) row

// One block per batch: init inv[b*L .. b*L+L) = -1, sync, scatter pos.
__global__ void init_build_inv_kernel(const int* __restrict__ pos, int* __restrict__ inv) {
    const int b = blockIdx.x;                         // 0..KB-1
    int* slice = inv + b * KL;
    for (int i = threadIdx.x; i < KL; i += blockDim.x)
        slice[i] = -1;
    __syncthreads();
    const int* prow = pos + b * KQ;
    for (int q = threadIdx.x; q < KQ; q += blockDim.x) {
        int p = prow[q] - 1;                          // 1-indexed -> 0-indexed
        slice[p] = q;
    }
}

__global__ void fused_write_kernel(const f32x4* __restrict__ kc, const f32x4* __restrict__ vc,
                                   const f32x4* __restrict__ kv, const f32x4* __restrict__ vv,
                                   const int* __restrict__ inv,
                                   f32x4* __restrict__ ko, f32x4* __restrict__ vo) {
    const long long n = TOT / 4;                      // 8,388,608 f32x4 per tensor
    const long long stride = (long long)gridDim.x * blockDim.x;
    for (long long i = (long long)blockIdx.x * blockDim.x + threadIdx.x; i < n; i += stride) {
        int bl = (int)(i >> 8);                       // / ROW4 (=256)
        int q = inv[bl];                              // cached load (reused by 4 waves/row)
        f32x4 kx, vx;
        if (q >= 0) {
            int b = bl >> 12;                         // / KL (=4096)
            long long s = ((long long)(b * KQ + q) << 8) + (i & (ROW4 - 1));
            kx = __builtin_nontemporal_load(&kv[s]);
            vx = __builtin_nontemporal_load(&vv[s]);
        } else {
            kx = __builtin_nontemporal_load(&kc[i]);
            vx = __builtin_nontemporal_load(&vc[i]);
        }
        __builtin_nontemporal_store(kx, &ko[i]);
        __builtin_nontemporal_store(vx, &vo[i]);
    }
}

extern "C" void kernel_launch(void* const* d_in, const int* in_sizes, int n_in,
                              void* d_out, int out_size, void* d_ws, size_t ws_size,
                              hipStream_t stream) {
    const float* kc  = (const float*)d_in[0];
    const float* vc  = (const float*)d_in[1];
    const float* kv  = (const float*)d_in[2];
    const float* vv  = (const float*)d_in[3];
    const int*   pos = (const int*)d_in[4];

    float* ko = (float*)d_out;
    float* vo = ko + TOT;

    int* inv = (int*)d_ws;                            // 128 KB needed; ws is preallocated scratch

    init_build_inv_kernel<<<KB, 256, 0, stream>>>(pos, inv);
    fused_write_kernel<<<4096, 256, 0, stream>>>(
        (const f32x4*)kc, (const f32x4*)vc,
        (const f32x4*)kv, (const f32x4*)vv,
        inv, (f32x4*)ko, (f32x4*)vo);
}